// Round 1
// baseline (1829.220 us; speedup 1.0000x reference)
//
#include <hip/hip_runtime.h>
#include <hip/hip_bf16.h>

// Problem constants (fixed by the reference): B=4 H=16 L=2048 D=64, temp=8.0
#define Bb 4
#define Hh 16
#define Ll 2048
#define Dd 64
#define MT 64              // query rows per workgroup (16 per wave)
#define KC 128             // keys staged per chunk
#define NCH (Ll / KC)      // 16 chunks

typedef float f32x4 __attribute__((ext_vector_type(4)));
typedef short s16x8 __attribute__((ext_vector_type(8)));

// round-to-nearest-even fp32 -> bf16 (finite inputs only)
static __device__ __forceinline__ short f2bf(float f) {
  unsigned u = __builtin_bit_cast(unsigned, f);
  u += 0x7fff + ((u >> 16) & 1);
  return (short)(u >> 16);
}

// stage 128x64 fp32 K rows -> bf16 LDS [128][72] (pad +8 keeps b128 reads 2-way)
static __device__ __forceinline__ void stage_K(const float* __restrict__ src,
                                               short (*Ks)[72], int tid) {
#pragma unroll
  for (int it = 0; it < 8; ++it) {
    int idx4 = tid + it * 256;       // float4 index 0..2047
    int n = idx4 >> 4;               // key row in chunk
    int d = (idx4 & 15) * 4;
    float4 v = *(const float4*)(src + n * Dd + d);
    short* dst = &Ks[n][d];
    dst[0] = f2bf(v.x); dst[1] = f2bf(v.y);
    dst[2] = f2bf(v.z); dst[3] = f2bf(v.w);
  }
}

__global__ __launch_bounds__(256) void sdpa_fused(
    const float* __restrict__ Qg, const float* __restrict__ Kg,
    const float* __restrict__ Vg, const unsigned char* __restrict__ Mg,
    float* __restrict__ out) {
  __shared__ short Ks[KC][72];        // 18432 B
  __shared__ short Vt[Dd][KC + 8];    // 17408 B, V transposed [d][k]
  __shared__ short Pt[4][16][40];     // 5120 B, per-wave P C->A layout bounce

  const int tid  = threadIdx.x;
  const int w    = tid >> 6;          // wave 0..3
  const int lane = tid & 63;
  const int m    = lane & 15;         // A-row / C-col lane index
  const int quad = lane >> 4;

  const int bh = blockIdx.x >> 5;     // 0..63  (b*16 + h); 32 q-tiles/head adjacent -> L2 reuse
  const int qt = blockIdx.x & 31;
  const int b  = bh >> 4;
  const int q0 = qt * MT;

  const float* Qh = Qg + (size_t)bh * Ll * Dd;
  const float* Kh = Kg + (size_t)bh * Ll * Dd;
  const float* Vh = Vg + (size_t)bh * Ll * Dd;
  const unsigned char* Mb = Mg + (size_t)b * Ll * Ll;
  float* res = out + (size_t)bh * Ll * Dd;
  float* att = out + (size_t)Bb * Hh * Ll * Dd + (size_t)bh * Ll * Ll;

  const int rowb = q0 + w * 16;       // this wave's 16-row strip base (within head)

  // ---- persistent Q fragments: A-layout lane holds Q[rowb+m][k = s*32 + quad*8 + j]
  s16x8 qf[2];
  {
    const float* qp = Qh + (size_t)(rowb + m) * Dd + quad * 8;
#pragma unroll
    for (int s = 0; s < 2; ++s) {
      float4 a = *(const float4*)(qp + s * 32);
      float4 c = *(const float4*)(qp + s * 32 + 4);
      qf[s][0] = f2bf(a.x); qf[s][1] = f2bf(a.y);
      qf[s][2] = f2bf(a.z); qf[s][3] = f2bf(a.w);
      qf[s][4] = f2bf(c.x); qf[s][5] = f2bf(c.y);
      qf[s][6] = f2bf(c.z); qf[s][7] = f2bf(c.w);
    }
  }

  // ================= phase 1: exp row sums (scores bounded -> no max needed) ==========
  float rowsum[4] = {0.f, 0.f, 0.f, 0.f};
  for (int ch = 0; ch < NCH; ++ch) {
    __syncthreads();
    stage_K(Kh + (size_t)ch * KC * Dd, Ks, tid);
    __syncthreads();
#pragma unroll
    for (int n0 = 0; n0 < KC; n0 += 16) {
      s16x8 kf0 = *(const s16x8*)&Ks[n0 + m][quad * 8];
      s16x8 kf1 = *(const s16x8*)&Ks[n0 + m][32 + quad * 8];
      f32x4 c = {0.f, 0.f, 0.f, 0.f};
      c = __builtin_amdgcn_mfma_f32_16x16x32_bf16(qf[0], kf0, c, 0, 0, 0);
      c = __builtin_amdgcn_mfma_f32_16x16x32_bf16(qf[1], kf1, c, 0, 0, 0);
      const unsigned char* mp =
          Mb + (size_t)(rowb + quad * 4) * Ll + ch * KC + n0 + m;
#pragma unroll
      for (int r = 0; r < 4; ++r) {
        float s = c[r] * 0.125f;             // /temperature
        if (mp[(size_t)r * Ll]) s = -1e9f;   // exp -> 0
        rowsum[r] += __expf(s);
      }
    }
  }
  // butterfly over the 16 lanes of each quad (cols 0..15 of each C row)
#pragma unroll
  for (int off = 1; off < 16; off <<= 1) {
#pragma unroll
    for (int r = 0; r < 4; ++r) rowsum[r] += __shfl_xor(rowsum[r], off, 64);
  }
  float linv[4];
#pragma unroll
  for (int r = 0; r < 4; ++r) linv[r] = 1.0f / rowsum[r];

  // ================= phase 2: recompute, normalize, write attention, PV ===============
  f32x4 oacc[4];
  const f32x4 zero4 = {0.f, 0.f, 0.f, 0.f};
#pragma unroll
  for (int dt = 0; dt < 4; ++dt) oacc[dt] = zero4;

  for (int ch = 0; ch < NCH; ++ch) {
    __syncthreads();
    stage_K(Kh + (size_t)ch * KC * Dd, Ks, tid);
    {  // stage V transposed: coalesced 256B global reads, b128 LDS stores (2-way = free)
      const float* src = Vh + (size_t)ch * KC * Dd;
      int d  = tid & 63;
      int kb = (tid >> 6) * 32;
#pragma unroll
      for (int p = 0; p < 4; ++p) {
        s16x8 pk;
#pragma unroll
        for (int j = 0; j < 8; ++j)
          pk[j] = f2bf(src[(size_t)(kb + p * 8 + j) * Dd + d]);
        *(s16x8*)&Vt[d][kb + p * 8] = pk;
      }
    }
    __syncthreads();
#pragma unroll
    for (int g = 0; g < 4; ++g) {            // 32-key groups -> one PV k-step
      float pv[2][4];
#pragma unroll
      for (int sub = 0; sub < 2; ++sub) {
        int n0 = g * 32 + sub * 16;
        s16x8 kf0 = *(const s16x8*)&Ks[n0 + m][quad * 8];
        s16x8 kf1 = *(const s16x8*)&Ks[n0 + m][32 + quad * 8];
        f32x4 c = {0.f, 0.f, 0.f, 0.f};
        c = __builtin_amdgcn_mfma_f32_16x16x32_bf16(qf[0], kf0, c, 0, 0, 0);
        c = __builtin_amdgcn_mfma_f32_16x16x32_bf16(qf[1], kf1, c, 0, 0, 0);
        const unsigned char* mp =
            Mb + (size_t)(rowb + quad * 4) * Ll + ch * KC + n0 + m;
#pragma unroll
        for (int r = 0; r < 4; ++r) {
          float s = c[r] * 0.125f;
          if (mp[(size_t)r * Ll]) s = -1e9f;
          float p = __expf(s) * linv[r];
          pv[sub][r] = p;
          // C layout (row=quad*4+r, col=m) -> LDS; reread in A layout below
          Pt[w][quad * 4 + r][sub * 16 + m] = f2bf(p);
        }
      }
      // wave-local LDS RAW: drain DS queue before A-layout reads
      asm volatile("s_waitcnt lgkmcnt(0)" ::: "memory");
      s16x8 pf = *(const s16x8*)&Pt[w][m][quad * 8];   // P[m][k=quad*8+j]
#pragma unroll
      for (int dt = 0; dt < 4; ++dt) {
        s16x8 vf = *(const s16x8*)&Vt[dt * 16 + m][g * 32 + quad * 8];
        oacc[dt] = __builtin_amdgcn_mfma_f32_16x16x32_bf16(pf, vf, oacc[dt], 0, 0, 0);
      }
      // write normalized attention (fp32): 16 consecutive floats per quad-row
      float* ap = att + (size_t)(rowb + quad * 4) * Ll + ch * KC + g * 32 + m;
#pragma unroll
      for (int r = 0; r < 4; ++r) {
        ap[(size_t)r * Ll]      = pv[0][r];
        ap[(size_t)r * Ll + 16] = pv[1][r];
      }
    }
  }

  // ---- epilogue: res[row][d], C layout row=quad*4+r col=m
#pragma unroll
  for (int r = 0; r < 4; ++r) {
    float* rp = res + (size_t)(rowb + quad * 4 + r) * Dd;
#pragma unroll
    for (int dt = 0; dt < 4; ++dt) rp[dt * 16 + m] = oacc[dt][r];
  }
}

extern "C" void kernel_launch(void* const* d_in, const int* in_sizes, int n_in,
                              void* d_out, int out_size, void* d_ws, size_t ws_size,
                              hipStream_t stream) {
  const float* Q = (const float*)d_in[0];
  const float* K = (const float*)d_in[1];
  const float* V = (const float*)d_in[2];
  const unsigned char* M = (const unsigned char*)d_in[3];  // jnp.bool_ -> 1 byte
  float* out = (float*)d_out;  // [res | attention] concatenated

  dim3 grid(Bb * Hh * (Ll / MT));  // 2048 workgroups
  dim3 block(256);
  hipLaunchKernelGGL(sdpa_fused, grid, block, 0, stream, Q, K, V, M, out);
}